// Round 4
// baseline (84.717 us; speedup 1.0000x reference)
//
#include <hip/hip_runtime.h>

#define N 8192
#define D 64

// Kernel 1: G = S^T S (64x64) and t = column-sums(S) (64), accumulated into ws.
__global__ __launch_bounds__(256) void gram_kernel(const float* __restrict__ S,
                                                   float* __restrict__ G,
                                                   float* __restrict__ t) {
    __shared__ float rows[4][D];          // 4 staged rows
    const int tid = threadIdx.x;
    const int d = tid & 63;
    const int q = tid >> 6;               // 0..3 -> owns G rows q*16 .. q*16+15

    float acc[16];
#pragma unroll
    for (int m = 0; m < 16; ++m) acc[m] = 0.f;
    float tacc = 0.f;

    const int rows_per_block = N / gridDim.x;   // grid chosen to divide N
    const int row0 = blockIdx.x * rows_per_block;

    for (int j = row0; j < row0 + rows_per_block; j += 4) {
        // 256 threads load 4 contiguous rows (256 floats) coalesced
        rows[q][d] = S[(size_t)j * D + tid];
        __syncthreads();
#pragma unroll
        for (int r = 0; r < 4; ++r) {
            const float sd = rows[r][d];                // stride-1: conflict-free
            if (q == 0) tacc += sd;                     // column sums (each d once)
#pragma unroll
            for (int m = 0; m < 16; ++m)
                acc[m] += rows[r][q * 16 + m] * sd;     // same addr per wave: broadcast
        }
        __syncthreads();
    }

#pragma unroll
    for (int m = 0; m < 16; ++m)
        atomicAdd(&G[(q * 16 + m) * D + d], acc[m]);
    if (q == 0) atomicAdd(&t[d], tacc);
}

// Kernel 2: out[i,:] = (s_i @ G) / (s_i . t)
__global__ __launch_bounds__(256) void apply_kernel(const float* __restrict__ S,
                                                    const float* __restrict__ G,
                                                    const float* __restrict__ t,
                                                    float* __restrict__ out) {
    __shared__ float Gs[D * D];
    __shared__ float ts[D];
    const int tid = threadIdx.x;
    for (int i = tid; i < D * D; i += 256) Gs[i] = G[i];
    if (tid < D) ts[tid] = t[tid];
    __syncthreads();

    const int lane = tid & 63;
    const int wave = tid >> 6;                  // 0..3
    const int nwaves = gridDim.x * 4;

    for (int i = blockIdx.x * 4 + wave; i < N; i += nwaves) {
        const float v = S[(size_t)i * D + lane];
        float accv = 0.f;
        float rs = 0.f;
#pragma unroll
        for (int k = 0; k < D; ++k) {
            const float sk = __shfl(v, k, 64);  // constant lane -> readlane/broadcast
            accv += sk * Gs[k * D + lane];      // lanes stride-1: conflict-free
            rs += sk * ts[k];                   // uniform broadcast
        }
        out[(size_t)i * D + lane] = accv / rs;
    }
}

extern "C" void kernel_launch(void* const* d_in, const int* in_sizes, int n_in,
                              void* d_out, int out_size, void* d_ws, size_t ws_size,
                              hipStream_t stream) {
    const float* S = (const float*)d_in[0];
    float* out = (float*)d_out;
    float* G = (float*)d_ws;
    float* t = G + D * D;

    hipMemsetAsync(d_ws, 0, (D * D + D) * sizeof(float), stream);
    gram_kernel<<<64, 256, 0, stream>>>(S, G, t);
    apply_kernel<<<256, 256, 0, stream>>>(S, G, t, out);
}